// Round 7
// baseline (27.867 us; speedup 1.0000x reference)
//
#include <hip/hip_runtime.h>

#define NB 32
#define NC 64
#define NO 128
#define NK 9
#define NL 4096

#define OSPLIT 2
#define OPB (NO / OSPLIT)   // 64 output channels per block
#define LTILE 1024          // 256 threads * 4 floats
#define NLT (NL / LTILE)    // 4 l-tiles

typedef float vfloat4 __attribute__((ext_vector_type(4)));
typedef float vfloat2 __attribute__((ext_vector_type(2)));

// ---------- kernel 1: colsum[b][l] = sum_i x[b][i][l] ----------
// block 0 additionally computes evinv and the normalized wcn -> ws.
// 1024 blocks: (b, lt), lt in [0,32) covering 128 l each.
__global__ __launch_bounds__(256) void colsum_kernel(
    const float* __restrict__ x, const float* __restrict__ ev,
    const float* __restrict__ wc,
    float* __restrict__ colsum, float* __restrict__ evinv,
    float* __restrict__ wcn_ws)
{
    __shared__ vfloat4 part[8][32];
    __shared__ float red[4];

    const int bid = blockIdx.x;
    const int t = threadIdx.x;

    if (bid == 0) {
        // inv L2 norm of err_vector
        float s = 0.f;
#pragma unroll
        for (int r = 0; r < NL / 256; ++r) {
            float v = ev[r * 256 + t];
            s += v * v;
        }
#pragma unroll
        for (int off = 32; off > 0; off >>= 1) s += __shfl_down(s, off, 64);
        if ((t & 63) == 0) red[t >> 6] = s;
        // normalized weight_coeff rows -> workspace (read back via s_load in main)
        if (t < NO) {
            float w[NK]; float ss = 0.f;
#pragma unroll
            for (int k = 0; k < NK; ++k) { w[k] = wc[t * NK + k]; ss += w[k] * w[k]; }
            const float inv = rsqrtf(ss);
#pragma unroll
            for (int k = 0; k < NK; ++k) wcn_ws[t * NK + k] = w[k] * inv;
        }
        __syncthreads();
        if (t == 0) evinv[0] = rsqrtf(red[0] + red[1] + red[2] + red[3]);
    }

    const int b  = bid >> 5;          // 32 batches
    const int lt = bid & 31;          // 32 tiles of 128 l
    const int col = t & 31;           // float4 column in tile
    const int cg  = t >> 5;           // channel group (8 groups of 8)
    const int l = lt * 128 + col * 4;

    const float* xp = x + (size_t)b * NC * NL + (size_t)cg * 8 * NL + l;
    vfloat4 acc = (vfloat4){0.f, 0.f, 0.f, 0.f};
#pragma unroll
    for (int i = 0; i < 8; ++i) {
        vfloat4 v = __builtin_nontemporal_load(
            reinterpret_cast<const vfloat4*>(xp + (size_t)i * NL));
        acc += v;
    }
    part[cg][col] = acc;
    __syncthreads();
    if (t < 32) {
        vfloat4 s = part[0][t];
#pragma unroll
        for (int g = 1; g < 8; ++g) s += part[g][t];
        *reinterpret_cast<vfloat4*>(colsum + (size_t)b * NL + lt * 128 + t * 4) = s;
    }
}

// ---------- kernel 2: out[b,o,l] = evn[l] * sum_k wcn[o,k]*colsum[b,idx[k,l]] + bias[o]
// 256 blocks = 1/CU, no tail: (b, lt, og). 64 o-channels per block.
// Weights/bias via uniform s_load; inner FMA as vfloat2 pairs (v_pk_fma_f32).
__global__ __launch_bounds__(256) void gmconv_main_kernel(
    const float* __restrict__ wcn, const float* __restrict__ ev,
    const float* __restrict__ bias, const int* __restrict__ idx,
    const float* __restrict__ colsum, const float* __restrict__ evinv_p,
    float* __restrict__ out)
{
    __shared__ float csS[NL];        // 16 KB staged colsum[b]

    const int bid = blockIdx.x;
    const int og = bid & (OSPLIT - 1);        // 2 o-groups
    const int lt = (bid >> 1) & (NLT - 1);    // 4 l-tiles
    const int b  = bid >> 3;                  // 32 batches
    const int t  = threadIdx.x;

    // stage colsum[b] -> LDS (linear float4, conflict-free)
    const float* __restrict__ csg = colsum + (size_t)b * NL;
#pragma unroll
    for (int r = 0; r < NL / (4 * 256); ++r) {
        const int j = (r * 256 + t) * 4;
        *reinterpret_cast<vfloat4*>(&csS[j]) =
            *reinterpret_cast<const vfloat4*>(csg + j);
    }
    __syncthreads();

    const float evinv = evinv_p[0];
    const int l0 = lt * LTILE + t * 4;

    const vfloat4 e4 = *reinterpret_cast<const vfloat4*>(ev + l0);
    const float ex = e4.x * evinv, ey = e4.y * evinv,
                ez = e4.z * evinv, ew = e4.w * evinv;

    // gather once per (b,l) from LDS, pre-scaled by normalized err_vector
    vfloat2 g01[NK], g23[NK];
#pragma unroll
    for (int k = 0; k < NK; ++k) {
        const int4 iv = *reinterpret_cast<const int4*>(idx + k * NL + l0);
        g01[k] = (vfloat2){csS[iv.x] * ex, csS[iv.y] * ey};
        g23[k] = (vfloat2){csS[iv.z] * ez, csS[iv.w] * ew};
    }

    const int obase = og * OPB;
    float* op = out + ((size_t)b * NO + obase) * NL + l0;
#pragma unroll
    for (int o = 0; o < OPB; ++o) {
        const float* __restrict__ wr = wcn + (obase + o) * NK;  // uniform address
        vfloat2 a01 = (vfloat2){0.f, 0.f};
        vfloat2 a23 = (vfloat2){0.f, 0.f};
#pragma unroll
        for (int k = 0; k < NK; ++k) {
            const float w = wr[k];            // s_load, SGPR broadcast
            a01 += w * g01[k];                // v_pk_fma_f32
            a23 += w * g23[k];
        }
        const float bb = bias[obase + o];     // uniform -> s_load
        const vfloat4 r = (vfloat4){a01.x + bb, a01.y + bb, a23.x + bb, a23.y + bb};
        __builtin_nontemporal_store(r, reinterpret_cast<vfloat4*>(op));
        op += NL;
    }
}

extern "C" void kernel_launch(void* const* d_in, const int* in_sizes, int n_in,
                              void* d_out, int out_size, void* d_ws, size_t ws_size,
                              hipStream_t stream) {
    const float* x    = (const float*)d_in[0];   // [32,64,1,4096]
    const float* wc   = (const float*)d_in[1];   // [128,1,9]
    const float* ev   = (const float*)d_in[2];   // [1,4096]
    const float* bias = (const float*)d_in[3];   // [128]
    const int*   idx  = (const int*)d_in[4];     // [9,4096]
    float* out = (float*)d_out;                  // [32,128,1,4096]

    float* wsf    = (float*)d_ws;
    float* evinv  = wsf;           // 1 float
    float* wcn_ws = wsf + 64;      // 128*9 = 1152 floats
    float* colsum = wsf + 1344;    // NB*NL floats (aligned)

    hipLaunchKernelGGL(colsum_kernel, dim3(NB * 32), dim3(256), 0, stream,
                       x, ev, wc, colsum, evinv, wcn_ws);
    hipLaunchKernelGGL(gmconv_main_kernel, dim3(NB * NLT * OSPLIT), dim3(256), 0,
                       stream, wcn_ws, ev, bias, idx, colsum, evinv, out);
}

// Round 8
// 22.917 us; speedup vs baseline: 1.2160x; 1.2160x over previous
//
#include <hip/hip_runtime.h>

#define NB 32
#define NC 64
#define NO 128
#define NK 9
#define NL 4096

#define OSPLIT 4
#define OPB (NO / OSPLIT)   // 32 output channels per block
#define LTILE 1024          // 256 threads * 4 floats
#define NLT (NL / LTILE)    // 4 l-tiles

typedef float vfloat4 __attribute__((ext_vector_type(4)));
typedef float vfloat2 __attribute__((ext_vector_type(2)));

// ---------- kernel 1: colsum[b][l] = sum_i x[b][i][l] ----------
// 512 blocks (2/CU): (b, lt), lt in [0,16) covering 256 l each.
// col = t&63 -> each wave-instruction reads 1 KB CONTIGUOUS from one channel.
// block 0 additionally computes evinv and the normalized wcn -> ws.
__global__ __launch_bounds__(256) void colsum_kernel(
    const float* __restrict__ x, const float* __restrict__ ev,
    const float* __restrict__ wc,
    float* __restrict__ colsum, float* __restrict__ evinv,
    float* __restrict__ wcn_ws)
{
    __shared__ vfloat4 part[4][64];
    __shared__ float red[4];

    const int bid = blockIdx.x;
    const int t = threadIdx.x;

    if (bid == 0) {
        // inv L2 norm of err_vector
        float s = 0.f;
#pragma unroll
        for (int r = 0; r < NL / 256; ++r) {
            float v = ev[r * 256 + t];
            s += v * v;
        }
#pragma unroll
        for (int off = 32; off > 0; off >>= 1) s += __shfl_down(s, off, 64);
        if ((t & 63) == 0) red[t >> 6] = s;
        // normalized weight_coeff rows -> workspace (read back via s_load in main)
        if (t < NO) {
            float w[NK]; float ss = 0.f;
#pragma unroll
            for (int k = 0; k < NK; ++k) { w[k] = wc[t * NK + k]; ss += w[k] * w[k]; }
            const float inv = rsqrtf(ss);
#pragma unroll
            for (int k = 0; k < NK; ++k) wcn_ws[t * NK + k] = w[k] * inv;
        }
        __syncthreads();
        if (t == 0) evinv[0] = rsqrtf(red[0] + red[1] + red[2] + red[3]);
    }

    const int b  = bid >> 4;          // 32 batches
    const int lt = bid & 15;          // 16 tiles of 256 l
    const int col = t & 63;           // float4 column in tile (64 per wave)
    const int cg  = t >> 6;           // channel group (4 groups of 16)
    const int l = lt * 256 + col * 4;

    const float* xp = x + (size_t)b * NC * NL + (size_t)cg * 16 * NL + l;
    vfloat4 acc = (vfloat4){0.f, 0.f, 0.f, 0.f};
#pragma unroll
    for (int i = 0; i < 16; ++i) {
        vfloat4 v = __builtin_nontemporal_load(
            reinterpret_cast<const vfloat4*>(xp + (size_t)i * NL));
        acc += v;
    }
    part[cg][col] = acc;
    __syncthreads();
    if (t < 64) {
        vfloat4 s = part[0][t];
#pragma unroll
        for (int g = 1; g < 4; ++g) s += part[g][t];
        *reinterpret_cast<vfloat4*>(colsum + (size_t)b * NL + lt * 256 + t * 4) = s;
    }
}

// ---------- kernel 2: out[b,o,l] = evn[l] * sum_k wcn[o,k]*colsum[b,idx[k,l]] + bias[o]
// 512 blocks (2/CU): (b, lt, og). Weights/bias via uniform s_load.
// idx/ev loads hoisted BEFORE the staging barrier to overlap their latency.
__global__ __launch_bounds__(256) void gmconv_main_kernel(
    const float* __restrict__ wcn, const float* __restrict__ ev,
    const float* __restrict__ bias, const int* __restrict__ idx,
    const float* __restrict__ colsum, const float* __restrict__ evinv_p,
    float* __restrict__ out)
{
    __shared__ float csS[NL];        // 16 KB staged colsum[b]

    const int bid = blockIdx.x;
    const int og = bid & (OSPLIT - 1);        // 4 o-groups
    const int lt = (bid >> 2) & (NLT - 1);    // 4 l-tiles
    const int b  = bid >> 4;                  // 32 batches
    const int t  = threadIdx.x;

    const float evinv = evinv_p[0];           // uniform -> s_load, early
    const int l0 = lt * LTILE + t * 4;

    // issue independent loads BEFORE staging so their latency overlaps it
    const vfloat4 e4 = *reinterpret_cast<const vfloat4*>(ev + l0);
    int4 iv[NK];
#pragma unroll
    for (int k = 0; k < NK; ++k)
        iv[k] = *reinterpret_cast<const int4*>(idx + k * NL + l0);

    // stage colsum[b] -> LDS (linear float4, conflict-free)
    const float* __restrict__ csg = colsum + (size_t)b * NL;
#pragma unroll
    for (int r = 0; r < NL / (4 * 256); ++r) {
        const int j = (r * 256 + t) * 4;
        *reinterpret_cast<vfloat4*>(&csS[j]) =
            *reinterpret_cast<const vfloat4*>(csg + j);
    }
    __syncthreads();

    const float ex = e4.x * evinv, ey = e4.y * evinv,
                ez = e4.z * evinv, ew = e4.w * evinv;

    // gather from LDS, pre-scaled by normalized err_vector
    vfloat2 g01[NK], g23[NK];
#pragma unroll
    for (int k = 0; k < NK; ++k) {
        g01[k] = (vfloat2){csS[iv[k].x] * ex, csS[iv[k].y] * ey};
        g23[k] = (vfloat2){csS[iv[k].z] * ez, csS[iv[k].w] * ew};
    }

    const int obase = og * OPB;
    float* op = out + ((size_t)b * NO + obase) * NL + l0;
#pragma unroll
    for (int o = 0; o < OPB; ++o) {
        const float* __restrict__ wr = wcn + (obase + o) * NK;  // uniform address
        vfloat2 a01 = (vfloat2){0.f, 0.f};
        vfloat2 a23 = (vfloat2){0.f, 0.f};
#pragma unroll
        for (int k = 0; k < NK; ++k) {
            const float w = wr[k];            // s_load, SGPR broadcast -> v_pk_fma_f32
            a01 += w * g01[k];
            a23 += w * g23[k];
        }
        const float bb = bias[obase + o];     // uniform -> s_load
        const vfloat4 r = (vfloat4){a01.x + bb, a01.y + bb, a23.x + bb, a23.y + bb};
        __builtin_nontemporal_store(r, reinterpret_cast<vfloat4*>(op));
        op += NL;
    }
}

extern "C" void kernel_launch(void* const* d_in, const int* in_sizes, int n_in,
                              void* d_out, int out_size, void* d_ws, size_t ws_size,
                              hipStream_t stream) {
    const float* x    = (const float*)d_in[0];   // [32,64,1,4096]
    const float* wc   = (const float*)d_in[1];   // [128,1,9]
    const float* ev   = (const float*)d_in[2];   // [1,4096]
    const float* bias = (const float*)d_in[3];   // [128]
    const int*   idx  = (const int*)d_in[4];     // [9,4096]
    float* out = (float*)d_out;                  // [32,128,1,4096]

    float* wsf    = (float*)d_ws;
    float* evinv  = wsf;           // 1 float
    float* wcn_ws = wsf + 64;      // 128*9 = 1152 floats
    float* colsum = wsf + 1344;    // NB*NL floats (aligned)

    hipLaunchKernelGGL(colsum_kernel, dim3(NB * 16), dim3(256), 0, stream,
                       x, ev, wc, colsum, evinv, wcn_ws);
    hipLaunchKernelGGL(gmconv_main_kernel, dim3(NB * NLT * OSPLIT), dim3(256), 0,
                       stream, wcn_ws, ev, bias, idx, colsum, evinv, out);
}